// Round 13
// baseline (86.353 us; speedup 1.0000x reference)
//
#include <hip/hip_runtime.h>

// Encoder_29661044146233 — round 13: r12 + standalone streaming cast pass.
//  conv1's INM0 staging (46 f32 gathers + pack per thread) was 5-6x slower per row
//  than conv2's INM1 path. Fix: grid-stride cast kernel input/offset f32 -> packed
//  bf16 q-order X0; conv1 becomes INM=1 (identical structure to conv2, L3-hot input).
//  All conv/graph code is r12-verbatim.

static constexpr int Jn   = 22;
static constexpr int C4   = 88;     // q-order: q<66 node(j=q/3,c=q%3), q>=66 edge(j=q-66)
static constexpr int KK   = 352;
static constexpr int NPAD = 96;
static constexpr int LROW = 88;     // LDS X row stride in ushorts (176 B, dense)
static constexpr int YROW = 101;    // Ytile row stride in floats
static constexpr int WSWZ = 2 * 11 * 3 * 64 * 8;   // 33792 bf16 elements per conv

typedef __attribute__((ext_vector_type(8))) short    short8;
typedef __attribute__((ext_vector_type(4))) float    floatx4;
typedef __attribute__((ext_vector_type(4))) unsigned uintx4;

__device__ constexpr int TOPc[Jn] = {0,0,1,2,3,4,0,6,7,8,0,10,11,12,12,14,15,16,12,18,19,20};

__device__ __forceinline__ unsigned short f2bf(float f) {
    unsigned u = __builtin_bit_cast(unsigned, f);
    unsigned r = (u + 0x7FFFu + ((u >> 16) & 1u)) >> 16;
    return (unsigned short)r;
}
__device__ __forceinline__ int qmap(int q) {
    return (q < 66) ? 4 * (q / 3) + (q % 3) : 4 * (q - 66) + 3;
}

struct GW {
    const float *n2n_w, *n2n_b, *e2n_we, *e2n_wn, *e2n_b;
    const float *n2e_wn, *n2e_we, *n2e_b, *lin_w, *lin_b;
};

// ---- streaming cast: (input f32 (B,F,66), offset f32 (B,F,22)) -> X0 bf16 (B,F,88) ----
// one 16B output chunk (8 bf16) per thread; fully coalesced, no LDS, no barriers.
__global__ __launch_bounds__(256)
void cast_input(const float* __restrict__ xf, const float* __restrict__ xoff,
                unsigned short* __restrict__ x0, int total)   // total = B*F*11 chunks
{
    const int c = blockIdx.x * 256 + threadIdx.x;
    if (c >= total) return;
    const int row = c / 11, qp = c - row * 11;
    const float* nsrc = xf   + (size_t)row * 66;
    const float* esrc = xoff + (size_t)row * 22;
    uintx4 u;
#pragma unroll
    for (int k = 0; k < 4; ++k) {
        const int qa = qp * 8 + 2 * k, qb = qa + 1;
        const float va = (qa < 66) ? nsrc[qa] : esrc[qa - 66];
        const float vb = (qb < 66) ? nsrc[qb] : esrc[qb - 66];
        u[k] = (unsigned)f2bf(va) | ((unsigned)f2bf(vb) << 16);
    }
    *reinterpret_cast<uintx4*>(x0 + (size_t)c * 8) = u;
}

// ---- prep: weights -> bf16 swizzled MFMA-fragment order [nh][kt][nti][lane][j] ----
__global__ __launch_bounds__(256)
void prep_weights(const float* __restrict__ w1, const float* __restrict__ w2,
                  const float* __restrict__ w3,
                  const float* __restrict__ b1, const float* __restrict__ b2,
                  const float* __restrict__ b3,
                  unsigned short* __restrict__ wo, float* __restrict__ bo)
{
    const int i = blockIdx.x * 256 + threadIdx.x;
    if (i < 3 * WSWZ) {
        const int s = i / WSWZ, e = i - s * WSWZ;
        const int j = e & 7, t = e >> 3;
        const int lane = t & 63, t2 = t >> 6;
        const int nti = t2 % 3, t3 = t2 / 3;
        const int kt = t3 % 11, nh = t3 / 11;
        const int co = nh * 48 + nti * 16 + (lane & 15);
        const int k  = kt * 32 + 8 * (lane >> 4) + j;
        const int tap = k / C4, q = k - tap * C4;
        const float* w = (s == 0) ? w1 : (s == 1) ? w2 : w3;
        float v = 0.f;
        if (co < C4) v = w[((size_t)qmap(co) * C4 + qmap(q)) * 4 + tap];
        wo[i] = f2bf(v);
    } else if (i < 3 * WSWZ + 3 * NPAD) {
        const int jj = i - 3 * WSWZ;
        const int s = jj / NPAD, q = jj - s * NPAD;
        const float* bb = (s == 0) ? b1 : (s == 1) ? b2 : b3;
        bo[jj] = (q < C4) ? bb[qmap(q)] : 0.f;
    }
}

// ---------------- fused conv1d(k=4,s=2,pad 1,1) [+ graph block] ----------------
template<int FIN, int OUTM, int MTt>
__global__ __launch_bounds__(256, (MTt == 128 ? 2 : 4))
void conv_fused(const unsigned short* __restrict__ xbf,
                const unsigned short* __restrict__ bwz, const float* __restrict__ bias,
                void* __restrict__ yout, GW g)
{
    constexpr int FOUT  = FIN / 2;
    constexpr int NTILE = FOUT / MTt;
    constexpr int NFRt  = 2 * MTt + 2;
    constexpr int NMT   = MTt / 32;
    constexpr int CHK_N  = NFRt * 11;
    constexpr int NIT_C  = (CHK_N + 255) / 256;
    constexpr int NGRP   = 256 / MTt;
    constexpr int JPG    = (Jn + NGRP - 1) / NGRP;
    constexpr unsigned XBYTES = NFRt * LROW * 2;
    constexpr unsigned SMEM = (OUTM == 0)
        ? (MTt * YROW * 4 + MTt * C4 * 2)
        : (XBYTES + MTt * 66 * 4);

    __shared__ __align__(16) unsigned char smem[SMEM];
    unsigned short* Xs = reinterpret_cast<unsigned short*>(smem);
    float*          Yt = reinterpret_cast<float*>(smem);
    unsigned short* OutU = reinterpret_cast<unsigned short*>(smem + (size_t)MTt * YROW * 4);
    float*          OutF = reinterpret_cast<float*>(smem + XBYTES);

    const int tid = threadIdx.x;
    const int b   = blockIdx.x / NTILE;
    const int fo0 = (blockIdx.x - b * NTILE) * MTt;
    const int gf0 = 2 * fo0 - 1;

    // ---------------- stage X tile (uint4 copy, clamped + zeroed halo) ----------------
    {
        const uintx4* xsrc = reinterpret_cast<const uintx4*>(xbf) + (size_t)b * FIN * 11;
#pragma unroll
        for (int it = 0; it < NIT_C; ++it) {
            const int idx = tid + it * 256;
            if (idx < CHK_N) {
                const int lf = idx / 11, qq = idx - lf * 11;
                const int gf = gf0 + lf;
                const int gfc = min(max(gf, 0), FIN - 1);
                uintx4 v = xsrc[gfc * 11 + qq];
                if (gf != gfc) v = (uintx4){0u, 0u, 0u, 0u};
                *reinterpret_cast<uintx4*>(Xs + lf * LROW + qq * 8) = v;
            }
        }
    }
    __syncthreads();

    // ---------------- K-loop ----------------
    const int wid = tid >> 6, lane = tid & 63;
    const int l15 = lane & 15, h = lane >> 4;
    const int mhalf = wid >> 1, nhalf = wid & 1;

    floatx4 acc[NMT][3];
#pragma unroll
    for (int mt = 0; mt < NMT; ++mt)
#pragma unroll
        for (int nti = 0; nti < 3; ++nti)
            acc[mt][nti] = (floatx4){0.f, 0.f, 0.f, 0.f};

    const unsigned short* wb = bwz + ((size_t)nhalf * 33 * 64 + lane) * 8;

#pragma unroll
    for (int kt = 0; kt < 11; ++kt) {
        const int q   = 4 * kt + h;
        const int tap = (unsigned)q / 11u;
        const int ci0 = 8 * (q - 11 * tap);
        const int lfb = 2 * l15 + tap;

        short8 afr[NMT];
#pragma unroll
        for (int mt = 0; mt < NMT; ++mt)
            afr[mt] = *reinterpret_cast<const short8*>(
                Xs + (mhalf * MTt + mt * 32 + lfb) * LROW + ci0);

        short8 bfr[3];
#pragma unroll
        for (int nti = 0; nti < 3; ++nti)
            bfr[nti] = *reinterpret_cast<const short8*>(wb + (size_t)(kt * 3 + nti) * 64 * 8);

#pragma unroll
        for (int mt = 0; mt < NMT; ++mt)
#pragma unroll
            for (int nti = 0; nti < 3; ++nti)
                acc[mt][nti] = __builtin_amdgcn_mfma_f32_16x16x32_bf16(
                    afr[mt], bfr[nti], acc[mt][nti], 0, 0, 0);
    }

    // ---------------- epilogue ----------------
    if (OUTM == 1) {
#pragma unroll
        for (int mt = 0; mt < NMT; ++mt)
#pragma unroll
            for (int nti = 0; nti < 3; ++nti) {
                const int co = nhalf * 48 + nti * 16 + l15;
                if (co < 66) {
                    const float bi = bias[co];
#pragma unroll
                    for (int r = 0; r < 4; ++r) {
                        const int row = mhalf * (MTt / 2) + mt * 16 + 4 * h + r;
                        OutF[row * 66 + co] = acc[mt][nti][r] + bi;
                    }
                }
            }
        __syncthreads();
        float2* dstg = reinterpret_cast<float2*>(
            reinterpret_cast<float*>(yout) + (size_t)(b * FOUT + fo0) * 66);
        const float2* srcl = reinterpret_cast<const float2*>(OutF);
        constexpr int NOUT2 = MTt * 33;
#pragma unroll
        for (int it = 0; it < (NOUT2 + 255) / 256; ++it) {
            const int idx = tid + it * 256;
            if (idx < NOUT2) dstg[idx] = srcl[idx];
        }
        return;
    }

    __syncthreads();   // all X reads done before Yt overwrite
#pragma unroll
    for (int mt = 0; mt < NMT; ++mt)
#pragma unroll
        for (int nti = 0; nti < 3; ++nti) {
            const int co = nhalf * 48 + nti * 16 + l15;
            const float bi = bias[co];
#pragma unroll
            for (int r = 0; r < 4; ++r) {
                const int row = mhalf * (MTt / 2) + mt * 16 + 4 * h + r;
                Yt[row * YROW + co] = acc[mt][nti][r] + bi;
            }
        }
    __syncthreads();

    // graph block -> OutU (disjoint) -> flat uint4 copy
    {
        const int row = tid & (MTt - 1), grp = tid / MTt;
        const float* yr = Yt + row * YROW;

        float n2n[9], n2nb[3], e2we[3], e2wn[9], e2nb[3], newn[3], lin[18], linb[3];
#pragma unroll
        for (int i = 0; i < 9;  ++i) n2n[i]  = g.n2n_w[i];
#pragma unroll
        for (int i = 0; i < 3;  ++i) n2nb[i] = g.n2n_b[i];
#pragma unroll
        for (int i = 0; i < 3;  ++i) e2we[i] = g.e2n_we[i];
#pragma unroll
        for (int i = 0; i < 9;  ++i) e2wn[i] = g.e2n_wn[i];
#pragma unroll
        for (int i = 0; i < 3;  ++i) e2nb[i] = g.e2n_b[i];
#pragma unroll
        for (int i = 0; i < 3;  ++i) newn[i] = g.n2e_wn[i];
        const float newe = g.n2e_we[0];
        const float neb  = g.n2e_b[0];
#pragma unroll
        for (int i = 0; i < 18; ++i) lin[i]  = g.lin_w[i];
#pragma unroll
        for (int i = 0; i < 3;  ++i) linb[i] = g.lin_b[i];

#pragma unroll
        for (int i = 0; i < Jn; ++i) {
            if (i / JPG != grp) continue;
            float an0 = 0.f, an1 = 0.f, an2 = 0.f, ae = 0.f;
#pragma unroll
            for (int j = 1; j < Jn; ++j) {
                if (TOPc[j] == i) {
                    an0 += yr[3 * j]; an1 += yr[3 * j + 1];
                    an2 += yr[3 * j + 2]; ae += yr[66 + j];
                }
            }
            const float s0 = yr[3 * i], s1 = yr[3 * i + 1], s2 = yr[3 * i + 2], se = yr[66 + i];
            float f1[3], f2[3];
#pragma unroll
            for (int c = 0; c < 3; ++c) {
                f1[c] = an0 * n2n[c] + an1 * n2n[3 + c] + an2 * n2n[6 + c] + n2nb[c];
                f2[c] = ae * e2we[c] + s0 * e2wn[c] + s1 * e2wn[3 + c] + s2 * e2wn[6 + c] + e2nb[c];
            }
            float p0 = 0.f, p1 = 0.f, p2 = 0.f;
            if (i > 0) {
                const int p = TOPc[i];
                p0 = yr[3 * p]; p1 = yr[3 * p + 1]; p2 = yr[3 * p + 2];
            }
            const float ne = p0 * newn[0] + p1 * newn[1] + p2 * newn[2] + se * newe + neb;

            float o[3];
#pragma unroll
            for (int c = 0; c < 3; ++c)
                o[c] = f1[0] * lin[0 + c] + f1[1] * lin[3 + c] + f1[2] * lin[6 + c]
                     + f2[0] * lin[9 + c] + f2[1] * lin[12 + c] + f2[2] * lin[15 + c] + linb[c];

            OutU[row * C4 + 3 * i]     = f2bf(o[0]);
            OutU[row * C4 + 3 * i + 1] = f2bf(o[1]);
            OutU[row * C4 + 3 * i + 2] = f2bf(o[2]);
            OutU[row * C4 + 66 + i]    = f2bf(ne);
        }
    }
    __syncthreads();

    {
        uintx4* dstg = reinterpret_cast<uintx4*>(
            reinterpret_cast<unsigned short*>(yout) + (size_t)(b * FOUT + fo0) * C4);
        const uintx4* srcl = reinterpret_cast<const uintx4*>(OutU);
        constexpr int NOUT = MTt * 11;
#pragma unroll
        for (int it = 0; it < (NOUT + 255) / 256; ++it) {
            const int idx = tid + it * 256;
            if (idx < NOUT) dstg[idx] = srcl[idx];
        }
    }
}

extern "C" void kernel_launch(void* const* d_in, const int* in_sizes, int n_in,
                              void* d_out, int out_size, void* d_ws, size_t ws_size,
                              hipStream_t stream)
{
    (void)n_in; (void)out_size; (void)ws_size;

    const float* input  = (const float*)d_in[0];
    const float* offset = (const float*)d_in[1];
    const float* c1w = (const float*)d_in[2]; const float* c1b = (const float*)d_in[3];
    const float* c2w = (const float*)d_in[4]; const float* c2b = (const float*)d_in[5];
    const float* c3w = (const float*)d_in[6]; const float* c3b = (const float*)d_in[7];

    GW g1 { (const float*)d_in[8],  (const float*)d_in[9],  (const float*)d_in[10],
            (const float*)d_in[11], (const float*)d_in[12], (const float*)d_in[13],
            (const float*)d_in[14], (const float*)d_in[15], (const float*)d_in[16],
            (const float*)d_in[17] };
    GW g2 { (const float*)d_in[18], (const float*)d_in[19], (const float*)d_in[20],
            (const float*)d_in[21], (const float*)d_in[22], (const float*)d_in[23],
            (const float*)d_in[24], (const float*)d_in[25], (const float*)d_in[26],
            (const float*)d_in[27] };

    const int B = in_sizes[0] / (2048 * Jn * 3);   // 128

    unsigned short* wbf = (unsigned short*)d_ws;                  // 3*33792 bf16 swizzled
    float* pb = (float*)(wbf + (size_t)3 * WSWZ);                 // 3*[96] f32 permuted bias
    unsigned short* X0 = (unsigned short*)(pb + 3 * NPAD);        // (B,2048,88) bf16 = 46.1MB
    unsigned short* X1 = X0 + (size_t)B * 2048 * C4;              // (B,1024,88) bf16
    unsigned short* X2 = X1 + (size_t)B * 1024 * C4;              // (B, 512,88) bf16

    {
        const int tot = 3 * WSWZ + 3 * NPAD;
        prep_weights<<<(tot + 255) / 256, 256, 0, stream>>>(c1w, c2w, c3w, c1b, c2b, c3b, wbf, pb);
    }
    {
        const int total = B * 2048 * 11;
        cast_input<<<(total + 255) / 256, 256, 0, stream>>>(input, offset, X0, total);
    }

    conv_fused<2048, 0, 128><<<B * 8, 256, 0, stream>>>(X0, wbf, pb, X1, g1);
    conv_fused<1024, 0, 128><<<B * 4, 256, 0, stream>>>(X1, wbf + WSWZ, pb + NPAD, X2, g2);
    conv_fused<512, 1, 64><<<B * 4, 256, 0, stream>>>(X2, wbf + 2 * WSWZ, pb + 2 * NPAD, d_out, g2);
}

// Round 14
// 68.071 us; speedup vs baseline: 1.2686x; 1.2686x over previous
//
#include <hip/hip_runtime.h>

// Encoder_29661044146233 — round 14: cast fused into conv1 staging, per-chunk gather.
//  r13 showed INM1-style conv1 is fast (~22us) but the split cast kernel was slow
//  (scalar strided loads). Fix: INM0 staging = 12 chunk-units/thread, each unit
//  4 branchless float2 loads (node/edge addr select) + pack + ds_write_b128.
//  Small live-range per unit -> no spill-serialization (r9-r12's failure mode).
//  Everything else r12-verbatim.

static constexpr int Jn   = 22;
static constexpr int C4   = 88;     // q-order: q<66 node(j=q/3,c=q%3), q>=66 edge(j=q-66)
static constexpr int KK   = 352;
static constexpr int NPAD = 96;
static constexpr int LROW = 88;     // LDS X row stride in ushorts (176 B, dense)
static constexpr int YROW = 101;    // Ytile row stride in floats
static constexpr int WSWZ = 2 * 11 * 3 * 64 * 8;   // 33792 bf16 elements per conv

typedef __attribute__((ext_vector_type(8))) short    short8;
typedef __attribute__((ext_vector_type(4))) float    floatx4;
typedef __attribute__((ext_vector_type(4))) unsigned uintx4;

__device__ constexpr int TOPc[Jn] = {0,0,1,2,3,4,0,6,7,8,0,10,11,12,12,14,15,16,12,18,19,20};

__device__ __forceinline__ unsigned short f2bf(float f) {
    unsigned u = __builtin_bit_cast(unsigned, f);
    unsigned r = (u + 0x7FFFu + ((u >> 16) & 1u)) >> 16;
    return (unsigned short)r;
}
__device__ __forceinline__ int qmap(int q) {
    return (q < 66) ? 4 * (q / 3) + (q % 3) : 4 * (q - 66) + 3;
}

struct GW {
    const float *n2n_w, *n2n_b, *e2n_we, *e2n_wn, *e2n_b;
    const float *n2e_wn, *n2e_we, *n2e_b, *lin_w, *lin_b;
};

// ---- prep: weights -> bf16 swizzled MFMA-fragment order [nh][kt][nti][lane][j] ----
__global__ __launch_bounds__(256)
void prep_weights(const float* __restrict__ w1, const float* __restrict__ w2,
                  const float* __restrict__ w3,
                  const float* __restrict__ b1, const float* __restrict__ b2,
                  const float* __restrict__ b3,
                  unsigned short* __restrict__ wo, float* __restrict__ bo)
{
    const int i = blockIdx.x * 256 + threadIdx.x;
    if (i < 3 * WSWZ) {
        const int s = i / WSWZ, e = i - s * WSWZ;
        const int j = e & 7, t = e >> 3;
        const int lane = t & 63, t2 = t >> 6;
        const int nti = t2 % 3, t3 = t2 / 3;
        const int kt = t3 % 11, nh = t3 / 11;
        const int co = nh * 48 + nti * 16 + (lane & 15);
        const int k  = kt * 32 + 8 * (lane >> 4) + j;
        const int tap = k / C4, q = k - tap * C4;
        const float* w = (s == 0) ? w1 : (s == 1) ? w2 : w3;
        float v = 0.f;
        if (co < C4) v = w[((size_t)qmap(co) * C4 + qmap(q)) * 4 + tap];
        wo[i] = f2bf(v);
    } else if (i < 3 * WSWZ + 3 * NPAD) {
        const int jj = i - 3 * WSWZ;
        const int s = jj / NPAD, q = jj - s * NPAD;
        const float* bb = (s == 0) ? b1 : (s == 1) ? b2 : b3;
        bo[jj] = (q < C4) ? bb[qmap(q)] : 0.f;
    }
}

// ---------------- fused conv1d(k=4,s=2,pad 1,1) [+ graph block] ----------------
// INM 0: per-chunk gather-cast from f32 (input (B,F,66), offset (B,F,22))
// INM 1: uint4 copy from packed bf16 (B,F,88)
template<int FIN, int INM, int OUTM, int MTt>
__global__ __launch_bounds__(256, (MTt == 128 ? 2 : 4))
void conv_fused(const float* __restrict__ xf, const float* __restrict__ xoff,
                const unsigned short* __restrict__ xbf,
                const unsigned short* __restrict__ bwz, const float* __restrict__ bias,
                void* __restrict__ yout, GW g)
{
    constexpr int FOUT  = FIN / 2;
    constexpr int NTILE = FOUT / MTt;
    constexpr int NFRt  = 2 * MTt + 2;
    constexpr int NMT   = MTt / 32;
    constexpr int CHK_N  = NFRt * 11;
    constexpr int NIT_C  = (CHK_N + 255) / 256;
    constexpr int NGRP   = 256 / MTt;
    constexpr int JPG    = (Jn + NGRP - 1) / NGRP;
    constexpr unsigned XBYTES = NFRt * LROW * 2;
    constexpr unsigned SMEM = (OUTM == 0)
        ? (MTt * YROW * 4 + MTt * C4 * 2)
        : (XBYTES + MTt * 66 * 4);

    __shared__ __align__(16) unsigned char smem[SMEM];
    unsigned short* Xs = reinterpret_cast<unsigned short*>(smem);
    float*          Yt = reinterpret_cast<float*>(smem);
    unsigned short* OutU = reinterpret_cast<unsigned short*>(smem + (size_t)MTt * YROW * 4);
    float*          OutF = reinterpret_cast<float*>(smem + XBYTES);

    const int tid = threadIdx.x;
    const int b   = blockIdx.x / NTILE;
    const int fo0 = (blockIdx.x - b * NTILE) * MTt;
    const int gf0 = 2 * fo0 - 1;

    // ---------------- stage X tile ----------------
    if (INM == 0) {
        // gather-cast: per 16B output chunk, 4 branchless float2 loads + pack
        const float* nbase = xf   + (size_t)b * FIN * 66;
        const float* ebase = xoff + (size_t)b * FIN * 22;
#pragma unroll
        for (int it = 0; it < NIT_C; ++it) {
            const int idx = tid + it * 256;
            if (idx < CHK_N) {
                const int lf = idx / 11, qq = idx - lf * 11;
                const int gf = gf0 + lf;
                const int gfc = min(max(gf, 0), FIN - 1);
                const float* nrow = nbase + (size_t)gfc * 66;
                const float* erow = ebase + (size_t)gfc * 22;
                uintx4 u;
#pragma unroll
                for (int k = 0; k < 4; ++k) {
                    const int gq = qq * 8 + 2 * k;
                    const float* src = (gq >= 66) ? (erow + (gq - 66)) : (nrow + gq);
                    const float2 v = *reinterpret_cast<const float2*>(src);
                    u[k] = (unsigned)f2bf(v.x) | ((unsigned)f2bf(v.y) << 16);
                }
                if (gf != gfc) u = (uintx4){0u, 0u, 0u, 0u};
                *reinterpret_cast<uintx4*>(Xs + lf * LROW + qq * 8) = u;
            }
        }
    } else {
        const uintx4* xsrc = reinterpret_cast<const uintx4*>(xbf) + (size_t)b * FIN * 11;
#pragma unroll
        for (int it = 0; it < NIT_C; ++it) {
            const int idx = tid + it * 256;
            if (idx < CHK_N) {
                const int lf = idx / 11, qq = idx - lf * 11;
                const int gf = gf0 + lf;
                const int gfc = min(max(gf, 0), FIN - 1);
                uintx4 v = xsrc[gfc * 11 + qq];
                if (gf != gfc) v = (uintx4){0u, 0u, 0u, 0u};
                *reinterpret_cast<uintx4*>(Xs + lf * LROW + qq * 8) = v;
            }
        }
    }
    __syncthreads();

    // ---------------- K-loop ----------------
    const int wid = tid >> 6, lane = tid & 63;
    const int l15 = lane & 15, h = lane >> 4;
    const int mhalf = wid >> 1, nhalf = wid & 1;

    floatx4 acc[NMT][3];
#pragma unroll
    for (int mt = 0; mt < NMT; ++mt)
#pragma unroll
        for (int nti = 0; nti < 3; ++nti)
            acc[mt][nti] = (floatx4){0.f, 0.f, 0.f, 0.f};

    const unsigned short* wb = bwz + ((size_t)nhalf * 33 * 64 + lane) * 8;

#pragma unroll
    for (int kt = 0; kt < 11; ++kt) {
        const int q   = 4 * kt + h;
        const int tap = (unsigned)q / 11u;
        const int ci0 = 8 * (q - 11 * tap);
        const int lfb = 2 * l15 + tap;

        short8 afr[NMT];
#pragma unroll
        for (int mt = 0; mt < NMT; ++mt)
            afr[mt] = *reinterpret_cast<const short8*>(
                Xs + (mhalf * MTt + mt * 32 + lfb) * LROW + ci0);

        short8 bfr[3];
#pragma unroll
        for (int nti = 0; nti < 3; ++nti)
            bfr[nti] = *reinterpret_cast<const short8*>(wb + (size_t)(kt * 3 + nti) * 64 * 8);

#pragma unroll
        for (int mt = 0; mt < NMT; ++mt)
#pragma unroll
            for (int nti = 0; nti < 3; ++nti)
                acc[mt][nti] = __builtin_amdgcn_mfma_f32_16x16x32_bf16(
                    afr[mt], bfr[nti], acc[mt][nti], 0, 0, 0);
    }

    // ---------------- epilogue ----------------
    if (OUTM == 1) {
#pragma unroll
        for (int mt = 0; mt < NMT; ++mt)
#pragma unroll
            for (int nti = 0; nti < 3; ++nti) {
                const int co = nhalf * 48 + nti * 16 + l15;
                if (co < 66) {
                    const float bi = bias[co];
#pragma unroll
                    for (int r = 0; r < 4; ++r) {
                        const int row = mhalf * (MTt / 2) + mt * 16 + 4 * h + r;
                        OutF[row * 66 + co] = acc[mt][nti][r] + bi;
                    }
                }
            }
        __syncthreads();
        float2* dstg = reinterpret_cast<float2*>(
            reinterpret_cast<float*>(yout) + (size_t)(b * FOUT + fo0) * 66);
        const float2* srcl = reinterpret_cast<const float2*>(OutF);
        constexpr int NOUT2 = MTt * 33;
#pragma unroll
        for (int it = 0; it < (NOUT2 + 255) / 256; ++it) {
            const int idx = tid + it * 256;
            if (idx < NOUT2) dstg[idx] = srcl[idx];
        }
        return;
    }

    __syncthreads();   // all X reads done before Yt overwrite
#pragma unroll
    for (int mt = 0; mt < NMT; ++mt)
#pragma unroll
        for (int nti = 0; nti < 3; ++nti) {
            const int co = nhalf * 48 + nti * 16 + l15;
            const float bi = bias[co];
#pragma unroll
            for (int r = 0; r < 4; ++r) {
                const int row = mhalf * (MTt / 2) + mt * 16 + 4 * h + r;
                Yt[row * YROW + co] = acc[mt][nti][r] + bi;
            }
        }
    __syncthreads();

    // graph block -> OutU (disjoint) -> flat uint4 copy
    {
        const int row = tid & (MTt - 1), grp = tid / MTt;
        const float* yr = Yt + row * YROW;

        float n2n[9], n2nb[3], e2we[3], e2wn[9], e2nb[3], newn[3], lin[18], linb[3];
#pragma unroll
        for (int i = 0; i < 9;  ++i) n2n[i]  = g.n2n_w[i];
#pragma unroll
        for (int i = 0; i < 3;  ++i) n2nb[i] = g.n2n_b[i];
#pragma unroll
        for (int i = 0; i < 3;  ++i) e2we[i] = g.e2n_we[i];
#pragma unroll
        for (int i = 0; i < 9;  ++i) e2wn[i] = g.e2n_wn[i];
#pragma unroll
        for (int i = 0; i < 3;  ++i) e2nb[i] = g.e2n_b[i];
#pragma unroll
        for (int i = 0; i < 3;  ++i) newn[i] = g.n2e_wn[i];
        const float newe = g.n2e_we[0];
        const float neb  = g.n2e_b[0];
#pragma unroll
        for (int i = 0; i < 18; ++i) lin[i]  = g.lin_w[i];
#pragma unroll
        for (int i = 0; i < 3;  ++i) linb[i] = g.lin_b[i];

#pragma unroll
        for (int i = 0; i < Jn; ++i) {
            if (i / JPG != grp) continue;
            float an0 = 0.f, an1 = 0.f, an2 = 0.f, ae = 0.f;
#pragma unroll
            for (int j = 1; j < Jn; ++j) {
                if (TOPc[j] == i) {
                    an0 += yr[3 * j]; an1 += yr[3 * j + 1];
                    an2 += yr[3 * j + 2]; ae += yr[66 + j];
                }
            }
            const float s0 = yr[3 * i], s1 = yr[3 * i + 1], s2 = yr[3 * i + 2], se = yr[66 + i];
            float f1[3], f2[3];
#pragma unroll
            for (int c = 0; c < 3; ++c) {
                f1[c] = an0 * n2n[c] + an1 * n2n[3 + c] + an2 * n2n[6 + c] + n2nb[c];
                f2[c] = ae * e2we[c] + s0 * e2wn[c] + s1 * e2wn[3 + c] + s2 * e2wn[6 + c] + e2nb[c];
            }
            float p0 = 0.f, p1 = 0.f, p2 = 0.f;
            if (i > 0) {
                const int p = TOPc[i];
                p0 = yr[3 * p]; p1 = yr[3 * p + 1]; p2 = yr[3 * p + 2];
            }
            const float ne = p0 * newn[0] + p1 * newn[1] + p2 * newn[2] + se * newe + neb;

            float o[3];
#pragma unroll
            for (int c = 0; c < 3; ++c)
                o[c] = f1[0] * lin[0 + c] + f1[1] * lin[3 + c] + f1[2] * lin[6 + c]
                     + f2[0] * lin[9 + c] + f2[1] * lin[12 + c] + f2[2] * lin[15 + c] + linb[c];

            OutU[row * C4 + 3 * i]     = f2bf(o[0]);
            OutU[row * C4 + 3 * i + 1] = f2bf(o[1]);
            OutU[row * C4 + 3 * i + 2] = f2bf(o[2]);
            OutU[row * C4 + 66 + i]    = f2bf(ne);
        }
    }
    __syncthreads();

    {
        uintx4* dstg = reinterpret_cast<uintx4*>(
            reinterpret_cast<unsigned short*>(yout) + (size_t)(b * FOUT + fo0) * C4);
        const uintx4* srcl = reinterpret_cast<const uintx4*>(OutU);
        constexpr int NOUT = MTt * 11;
#pragma unroll
        for (int it = 0; it < (NOUT + 255) / 256; ++it) {
            const int idx = tid + it * 256;
            if (idx < NOUT) dstg[idx] = srcl[idx];
        }
    }
}

extern "C" void kernel_launch(void* const* d_in, const int* in_sizes, int n_in,
                              void* d_out, int out_size, void* d_ws, size_t ws_size,
                              hipStream_t stream)
{
    (void)n_in; (void)out_size; (void)ws_size;

    const float* input  = (const float*)d_in[0];
    const float* offset = (const float*)d_in[1];
    const float* c1w = (const float*)d_in[2]; const float* c1b = (const float*)d_in[3];
    const float* c2w = (const float*)d_in[4]; const float* c2b = (const float*)d_in[5];
    const float* c3w = (const float*)d_in[6]; const float* c3b = (const float*)d_in[7];

    GW g1 { (const float*)d_in[8],  (const float*)d_in[9],  (const float*)d_in[10],
            (const float*)d_in[11], (const float*)d_in[12], (const float*)d_in[13],
            (const float*)d_in[14], (const float*)d_in[15], (const float*)d_in[16],
            (const float*)d_in[17] };
    GW g2 { (const float*)d_in[18], (const float*)d_in[19], (const float*)d_in[20],
            (const float*)d_in[21], (const float*)d_in[22], (const float*)d_in[23],
            (const float*)d_in[24], (const float*)d_in[25], (const float*)d_in[26],
            (const float*)d_in[27] };

    const int B = in_sizes[0] / (2048 * Jn * 3);   // 128

    unsigned short* wbf = (unsigned short*)d_ws;                  // 3*33792 bf16 swizzled
    float* pb = (float*)(wbf + (size_t)3 * WSWZ);                 // 3*[96] f32 permuted bias
    unsigned short* X1 = (unsigned short*)(pb + 3 * NPAD);        // (B,1024,88) bf16
    unsigned short* X2 = X1 + (size_t)B * 1024 * C4;              // (B, 512,88) bf16

    {
        const int tot = 3 * WSWZ + 3 * NPAD;
        prep_weights<<<(tot + 255) / 256, 256, 0, stream>>>(c1w, c2w, c3w, c1b, c2b, c3b, wbf, pb);
    }

    conv_fused<2048, 0, 0, 128><<<B * 8, 256, 0, stream>>>(input, offset, nullptr,
                                                           wbf, pb, X1, g1);
    conv_fused<1024, 1, 0, 128><<<B * 4, 256, 0, stream>>>(nullptr, nullptr, X1,
                                                           wbf + WSWZ, pb + NPAD, X2, g2);
    conv_fused<512, 1, 1, 64><<<B * 4, 256, 0, stream>>>(nullptr, nullptr, X2,
                                                         wbf + 2 * WSWZ, pb + 2 * NPAD, d_out, g2);
}